// Round 13
// baseline (3348.223 us; speedup 1.0000x reference)
//
#include <hip/hip_runtime.h>
#include <cstddef>
#include <cstdint>

#define N_NODES 2048
#define BATCH   4
#define FDIM    256
#define HDIM    512
#define NEDGE   65536
#define BN_     8192
#define DT      0.25f

typedef __attribute__((ext_vector_type(8))) __bf16 bf16x8;
typedef __attribute__((ext_vector_type(4))) float f32x4;

__device__ __forceinline__ ushort f2bf(float f) {
    union { float f; unsigned u; } v; v.f = f;
    return (ushort)((v.u + 0x7FFF + ((v.u >> 16) & 1)) >> 16);   // RNE
}
__device__ __forceinline__ float bf2f(ushort u) {
    union { float f; unsigned u; } v; v.u = ((unsigned)u) << 16; return v.f;
}
__device__ __forceinline__ void gload16(const void* g, void* l) {
    __builtin_amdgcn_global_load_lds((const __attribute__((address_space(1))) void*)g,
                                     (__attribute__((address_space(3))) void*)l, 16, 0, 0);
}

// ---------------- Laplacian build ----------------
__global__ void edge_ew_deg(const float* __restrict__ attr, const int* __restrict__ eidx,
                            const float* __restrict__ w1, const float* __restrict__ b1,
                            const float* __restrict__ w2, const float* __restrict__ b2,
                            float* __restrict__ ew, float* __restrict__ deg) {
    int e = blockIdx.x * blockDim.x + threadIdx.x;
    if (e >= NEDGE) return;
    float a = attr[e];
    float s = b2[0];
#pragma unroll
    for (int k = 0; k < 32; ++k)
        s += fmaxf(fmaf(a, w1[k], b1[k]), 0.f) * w2[k];
    ew[e] = 1.f / (1.f + expf(-s));
    atomicAdd(&deg[eidx[NEDGE + e]], 1.f);
}

__global__ void dis_diag(const float* __restrict__ deg, float* __restrict__ dis,
                         float* __restrict__ L) {
    int n = blockIdx.x * blockDim.x + threadIdx.x;
    if (n >= N_NODES) return;
    float d = deg[n] + 1.f;
    dis[n] = rsqrtf(d);
    L[(size_t)n * N_NODES + n] = 1.f - 1.f / d;
}

__global__ void scatter_L(const int* __restrict__ eidx, const float* __restrict__ ew,
                          const float* __restrict__ dis, float* __restrict__ L) {
    int e = blockIdx.x * blockDim.x + threadIdx.x;
    if (e >= NEDGE) return;
    int r = eidx[e], c = eidx[NEDGE + e];
    atomicAdd(&L[(size_t)r * N_NODES + c], -dis[r] * ew[e] * dis[c]);
}

__global__ void ctxproj_kernel(const float* __restrict__ ctx, const float* __restrict__ w1,
                               const float* __restrict__ b1, float* __restrict__ out) {
    int b = blockIdx.x, h = threadIdx.x;
    const float* W = w1 + (size_t)FDIM * HDIM + h;
    const float* c = ctx + b * FDIM;
    float s = b1[h];
#pragma unroll 4
    for (int k = 0; k < FDIM; ++k)
        s = fmaf(c[k], W[(size_t)k * HDIM], s);
    out[b * HDIM + h] = s;
}

// out[c*R + r] = bf16(in[r*inStride + c]);  grid (R/64, C/64)
__global__ __launch_bounds__(256)
void transpose_cvt(const float* __restrict__ in, int inStride, ushort* __restrict__ out,
                   int R, int C) {
    __shared__ float tile[64][65];
    int r0 = blockIdx.x * 64, c0 = blockIdx.y * 64;
    int t = threadIdx.x, tr = t >> 4, tc = t & 15;
#pragma unroll
    for (int i = 0; i < 4; ++i) {
        float4 v = *(const float4*)&in[(size_t)(r0 + tr + i * 16) * inStride + c0 + tc * 4];
        tile[tr + i * 16][tc * 4 + 0] = v.x; tile[tr + i * 16][tc * 4 + 1] = v.y;
        tile[tr + i * 16][tc * 4 + 2] = v.z; tile[tr + i * 16][tc * 4 + 3] = v.w;
    }
    __syncthreads();
#pragma unroll
    for (int i = 0; i < 4; ++i) {
        int c = tr + i * 16;
        ushort4 o = make_ushort4(f2bf(tile[tc * 4 + 0][c]), f2bf(tile[tc * 4 + 1][c]),
                                 f2bf(tile[tc * 4 + 2][c]), f2bf(tile[tc * 4 + 3][c]));
        *(ushort4*)&out[(size_t)(c0 + c) * R + r0 + tc * 4] = o;
    }
}

__global__ void cvt_bf16(const float* __restrict__ in, ushort* __restrict__ out) {
    int i = blockIdx.x * blockDim.x + threadIdx.x;
    float4 v = ((const float4*)in)[i];
    ((ushort4*)out)[i] = make_ushort4(f2bf(v.x), f2bf(v.y), f2bf(v.z), f2bf(v.w));
}

// ---------------- combine: v = base + sum c_j * bf16(k_j); write [dstf fp32] [yi bf16] [yiT] ----
__global__ __launch_bounds__(256)
void combine_all(const float* __restrict__ base,
                 const ushort* p0, const ushort* p1, const ushort* p2,
                 const ushort* p3, const ushort* p4,
                 float c0, float c1, float c2, float c3, float c4,
                 float* __restrict__ dstf, ushort* __restrict__ yi,
                 ushort* __restrict__ yiT) {
    __shared__ ushort tile[64][68];
    int nb = blockIdx.x * 64, fb = blockIdx.y * 64, b = blockIdx.z;
    int t = threadIdx.x, tr = t >> 4, tc = t & 15;
#pragma unroll
    for (int i = 0; i < 4; ++i) {
        int nl = tr + i * 16;
        size_t fi = (((size_t)(b * N_NODES + nb + nl) * FDIM) + fb + tc * 4) >> 2;
        float4 v = ((const float4*)base)[fi];
        if (p0) { ushort4 q = ((const ushort4*)p0)[fi]; v.x = fmaf(c0,bf2f(q.x),v.x); v.y = fmaf(c0,bf2f(q.y),v.y); v.z = fmaf(c0,bf2f(q.z),v.z); v.w = fmaf(c0,bf2f(q.w),v.w); }
        if (p1) { ushort4 q = ((const ushort4*)p1)[fi]; v.x = fmaf(c1,bf2f(q.x),v.x); v.y = fmaf(c1,bf2f(q.y),v.y); v.z = fmaf(c1,bf2f(q.z),v.z); v.w = fmaf(c1,bf2f(q.w),v.w); }
        if (p2) { ushort4 q = ((const ushort4*)p2)[fi]; v.x = fmaf(c2,bf2f(q.x),v.x); v.y = fmaf(c2,bf2f(q.y),v.y); v.z = fmaf(c2,bf2f(q.z),v.z); v.w = fmaf(c2,bf2f(q.w),v.w); }
        if (p3) { ushort4 q = ((const ushort4*)p3)[fi]; v.x = fmaf(c3,bf2f(q.x),v.x); v.y = fmaf(c3,bf2f(q.y),v.y); v.z = fmaf(c3,bf2f(q.z),v.z); v.w = fmaf(c3,bf2f(q.w),v.w); }
        if (p4) { ushort4 q = ((const ushort4*)p4)[fi]; v.x = fmaf(c4,bf2f(q.x),v.x); v.y = fmaf(c4,bf2f(q.y),v.y); v.z = fmaf(c4,bf2f(q.z),v.z); v.w = fmaf(c4,bf2f(q.w),v.w); }
        if (dstf) ((float4*)dstf)[fi] = v;
        ushort4 o = make_ushort4(f2bf(v.x), f2bf(v.y), f2bf(v.z), f2bf(v.w));
        if (yi) ((ushort4*)yi)[fi] = o;
        tile[nl][tc * 4 + 0] = o.x; tile[nl][tc * 4 + 1] = o.y;
        tile[nl][tc * 4 + 2] = o.z; tile[nl][tc * 4 + 3] = o.w;
    }
    __syncthreads();
    if (!yiT) return;
#pragma unroll
    for (int i = 0; i < 4; ++i) {
        int fl = tr + i * 16;
        ushort4 o = make_ushort4(tile[tc * 4 + 0][fl], tile[tc * 4 + 1][fl],
                                 tile[tc * 4 + 2][fl], tile[tc * 4 + 3][fl]);
        *(ushort4*)&yiT[((size_t)(b * FDIM + fb + fl) * N_NODES) + nb + tc * 4] = o;
    }
}

// ---------------- bf16 MFMA GEMM: C[M,N] = A[M,K] @ BT[N,K]^T ----------------
// BIAS: 0 none; 1 bias[col]; 3 split (col<HDIM: bias[(row>>11)*HDIM+col], else bias2[col-HDIM])
// EPI: 0 fp32 store; 1 bf16 store; 2 diffusion RMW: ks[(b*2048+n)*256+f] -= dc[b*2048+n]*acc
template<int BM, int BN, int BK, int WM, int WN, int BIAS, int EPI>
__global__ __launch_bounds__(256)
void gemm(const ushort* __restrict__ A, const ushort* __restrict__ BT,
          const float* __restrict__ bias, const float* __restrict__ bias2,
          void* __restrict__ C, int N, int K, long sA, long sB, long sC) {
    constexpr int MR  = BM / WM / 16;
    constexpr int NR  = BN / WN / 16;
    constexpr int CPR = BK / 8;
    constexpr int ALD = BM * CPR / 256;
    constexpr int BLD = BN * CPR / 256;
    constexpr int KK  = BK / 32;
    __shared__ ushort As[BM * BK];
    __shared__ ushort Bs[BN * BK];
    const ushort* Ag = A + (size_t)blockIdx.z * sA;
    const ushort* Bg = BT + (size_t)blockIdx.z * sB;
    const int tid = threadIdx.x;
    const int lane = tid & 63, wid = tid >> 6;
    const int wn = wid % WN, wm = wid / WN;
    const int r15 = lane & 15, g = lane >> 4;
    const int rowBase = blockIdx.y * BM, colBase = blockIdx.x * BN;

    f32x4 acc[MR][NR];
#pragma unroll
    for (int m = 0; m < MR; ++m)
#pragma unroll
        for (int n = 0; n < NR; ++n) acc[m][n] = (f32x4){0.f, 0.f, 0.f, 0.f};

    for (int k0 = 0; k0 < K; k0 += BK) {
#pragma unroll
        for (int c = 0; c < ALD; ++c) {
            int ci = (wid * ALD + c) * 64 + lane;
            int row = ci / CPR, ch = ci % CPR;
            gload16(Ag + (size_t)(rowBase + row) * K + k0 + ((ch ^ (row & 7)) << 3),
                    &As[((wid * ALD + c) * 64) * 8]);
        }
#pragma unroll
        for (int c = 0; c < BLD; ++c) {
            int ci = (wid * BLD + c) * 64 + lane;
            int row = ci / CPR, ch = ci % CPR;
            gload16(Bg + (size_t)(colBase + row) * K + k0 + ((ch ^ (row & 7)) << 3),
                    &Bs[((wid * BLD + c) * 64) * 8]);
        }
        __syncthreads();
#pragma unroll
        for (int kk = 0; kk < KK; ++kk) {
            bf16x8 af[MR], bfr[NR];
#pragma unroll
            for (int m = 0; m < MR; ++m) {
                int lr = wm * (BM / WM) + m * 16 + r15;
                int off = lr * (BK * 2) + ((kk * 64 + g * 16) ^ ((lr & 7) << 4));
                af[m] = *(const bf16x8*)((const char*)As + off);
            }
#pragma unroll
            for (int n = 0; n < NR; ++n) {
                int br = wn * (BN / WN) + n * 16 + r15;
                int off = br * (BK * 2) + ((kk * 64 + g * 16) ^ ((br & 7) << 4));
                bfr[n] = *(const bf16x8*)((const char*)Bs + off);
            }
#pragma unroll
            for (int m = 0; m < MR; ++m)
#pragma unroll
                for (int n = 0; n < NR; ++n)
                    acc[m][n] = __builtin_amdgcn_mfma_f32_16x16x32_bf16(
                        af[m], bfr[n], acc[m][n], 0, 0, 0);
        }
        __syncthreads();
    }
    if (EPI == 2) {
        int b = colBase >> 8;
        ushort* ks = (ushort*)C;
#pragma unroll
        for (int m = 0; m < MR; ++m) {
            int row = rowBase + wm * (BM / WM) + m * 16 + g * 4;
            float4 dcv = *(const float4*)&bias2[b * N_NODES + row];
            float dca[4] = {dcv.x, dcv.y, dcv.z, dcv.w};
#pragma unroll
            for (int n = 0; n < NR; ++n) {
                int col = colBase + wn * (BN / WN) + n * 16 + r15;
                int f = col & 255;
#pragma unroll
                for (int r = 0; r < 4; ++r) {
                    size_t idx = ((size_t)(b * N_NODES + row + r)) * 256 + f;
                    ks[idx] = f2bf(bf2f(ks[idx]) - dca[r] * acc[m][n][r]);
                }
            }
        }
        return;
    }
#pragma unroll
    for (int m = 0; m < MR; ++m) {
        int row = rowBase + wm * (BM / WM) + m * 16 + g * 4;
#pragma unroll
        for (int n = 0; n < NR; ++n) {
            int col = colBase + wn * (BN / WN) + n * 16 + r15;
            float bv = 0.f;
            if (BIAS == 1) bv = bias[col];
            if (BIAS == 3) bv = (col < HDIM) ? bias[(row >> 11) * HDIM + col]
                                             : bias2[col - HDIM];
#pragma unroll
            for (int r = 0; r < 4; ++r) {
                float v = acc[m][n][r] + bv;
                if (EPI == 1) ((ushort*)C)[(size_t)blockIdx.z * sC + (size_t)(row + r) * N + col] = f2bf(v);
                else          ((float*)C)[(size_t)blockIdx.z * sC + (size_t)(row + r) * N + col] = v;
            }
        }
    }
}

// ---------------- LN-fused GEMM: C[64rows, N] = LN(A[rows,0:KF]) @ BT^T + bias ----------------
// A staged FULL-K once (64 x KF, swizzled source), per-row LN stats by lane-quads
// (shuffle-only), in-place normalize (gamma via de-swizzled index), then B-tiled K-loop.
// DCF: also dcoef[row] = sigmoid(relu(A[row, 512:768]) . w2 + b2), written by blockIdx.x==0.
// BM=64, 4 waves (WM=2 x WN=2). LDS = 64*KF*2 + BN*BK*2 = 80KB at KF=512,BN=64,BK=128.
template<int KF, int ASTR, int BN, int BK, int DCF>
__global__ __launch_bounds__(256)
void gemm_ln(const ushort* __restrict__ A, const ushort* __restrict__ BT,
             const float* __restrict__ lng, const float* __restrict__ lnb,
             const float* __restrict__ bias,
             const float* __restrict__ w2, const float* __restrict__ b2,
             float* __restrict__ dcout, ushort* __restrict__ C, int N) {
    constexpr int CPR  = KF / 8;             // A chunks per row
    constexpr int AIT  = 64 * CPR / 256;     // A staging iters
    constexpr int BCPR = BK / 8;
    constexpr int BIT  = BN * BCPR / 256;
    constexpr int KK   = BK / 32;
    constexpr int MR = 2, NR = BN / 2 / 16;
    __shared__ ushort As[64 * KF];
    __shared__ ushort Bs[BN * BK];
    const int tid = threadIdx.x;
    const int lane = tid & 63, wid = tid >> 6;
    const int wn = wid & 1, wm = wid >> 1;
    const int r15 = lane & 15, g = lane >> 4;
    const int rowBase = blockIdx.y * 64, colBase = blockIdx.x * BN;

    // ---- stage full-K A (source-swizzled) ----
#pragma unroll
    for (int c = 0; c < AIT; ++c) {
        int base = c * 256 + wid * 64;
        int ci = base + lane;
        int row = ci / CPR, ch = ci % CPR;
        gload16(A + (size_t)(rowBase + row) * ASTR + ((ch ^ (row & 7)) << 3),
                &As[base * 8]);
    }
    __syncthreads();

    // ---- per-row LN stats + normalize (quad of lanes per row) ----
    {
        const int row = tid >> 2, q = tid & 3;
        const int c0 = q * (CPR / 4), c1 = c0 + CPR / 4;
        float s = 0.f, s2 = 0.f;
        for (int ch = c0; ch < c1; ++ch) {
            uint4 pk = *(const uint4*)&As[row * KF + ch * 8];
            float x0 = bf2f((ushort)(pk.x & 0xffff)), x1 = bf2f((ushort)(pk.x >> 16));
            float x2 = bf2f((ushort)(pk.y & 0xffff)), x3 = bf2f((ushort)(pk.y >> 16));
            float x4 = bf2f((ushort)(pk.z & 0xffff)), x5 = bf2f((ushort)(pk.z >> 16));
            float x6 = bf2f((ushort)(pk.w & 0xffff)), x7 = bf2f((ushort)(pk.w >> 16));
            s  += (x0 + x1) + (x2 + x3) + (x4 + x5) + (x6 + x7);
            s2 += (x0*x0 + x1*x1) + (x2*x2 + x3*x3) + (x4*x4 + x5*x5) + (x6*x6 + x7*x7);
        }
        float d = 0.f;
        if (DCF) {
            const ushort* hr = A + (size_t)(rowBase + row) * ASTR + 512 + q * 64;
#pragma unroll
            for (int j = 0; j < 8; ++j) {
                uint4 pk = *(const uint4*)&hr[j * 8];
                const float* wv = w2 + q * 64 + j * 8;
                d += fmaxf(bf2f((ushort)(pk.x & 0xffff)), 0.f) * wv[0]
                   + fmaxf(bf2f((ushort)(pk.x >> 16)),    0.f) * wv[1]
                   + fmaxf(bf2f((ushort)(pk.y & 0xffff)), 0.f) * wv[2]
                   + fmaxf(bf2f((ushort)(pk.y >> 16)),    0.f) * wv[3]
                   + fmaxf(bf2f((ushort)(pk.z & 0xffff)), 0.f) * wv[4]
                   + fmaxf(bf2f((ushort)(pk.z >> 16)),    0.f) * wv[5]
                   + fmaxf(bf2f((ushort)(pk.w & 0xffff)), 0.f) * wv[6]
                   + fmaxf(bf2f((ushort)(pk.w >> 16)),    0.f) * wv[7];
            }
        }
        s  += __shfl_xor(s, 1);  s  += __shfl_xor(s, 2);
        s2 += __shfl_xor(s2, 1); s2 += __shfl_xor(s2, 2);
        if (DCF) {
            d += __shfl_xor(d, 1); d += __shfl_xor(d, 2);
            if (q == 0 && blockIdx.x == 0)
                dcout[rowBase + row] = 1.f / (1.f + expf(-(d + b2[0])));
        }
        float mu  = s * (1.f / KF);
        float inv = rsqrtf(fmaf(-mu, mu, s2 * (1.f / KF)) + 1e-5f);
        for (int ch = c0; ch < c1; ++ch) {
            int gk = (ch ^ (row & 7)) * 8;             // de-swizzled element index
            uint4 pk = *(const uint4*)&As[row * KF + ch * 8];
            float4 ga = *(const float4*)&lng[gk], gb = *(const float4*)&lng[gk + 4];
            float4 ba = *(const float4*)&lnb[gk], bb = *(const float4*)&lnb[gk + 4];
            float v0 = fmaxf(fmaf((bf2f((ushort)(pk.x & 0xffff)) - mu) * inv, ga.x, ba.x), 0.f);
            float v1 = fmaxf(fmaf((bf2f((ushort)(pk.x >> 16))    - mu) * inv, ga.y, ba.y), 0.f);
            float v2 = fmaxf(fmaf((bf2f((ushort)(pk.y & 0xffff)) - mu) * inv, ga.z, ba.z), 0.f);
            float v3 = fmaxf(fmaf((bf2f((ushort)(pk.y >> 16))    - mu) * inv, ga.w, ba.w), 0.f);
            float v4 = fmaxf(fmaf((bf2f((ushort)(pk.z & 0xffff)) - mu) * inv, gb.x, bb.x), 0.f);
            float v5 = fmaxf(fmaf((bf2f((ushort)(pk.z >> 16))    - mu) * inv, gb.y, bb.y), 0.f);
            float v6 = fmaxf(fmaf((bf2f((ushort)(pk.w & 0xffff)) - mu) * inv, gb.z, bb.z), 0.f);
            float v7 = fmaxf(fmaf((bf2f((ushort)(pk.w >> 16))    - mu) * inv, gb.w, bb.w), 0.f);
            uint4 o;
            o.x = (unsigned)f2bf(v0) | ((unsigned)f2bf(v1) << 16);
            o.y = (unsigned)f2bf(v2) | ((unsigned)f2bf(v3) << 16);
            o.z = (unsigned)f2bf(v4) | ((unsigned)f2bf(v5) << 16);
            o.w = (unsigned)f2bf(v6) | ((unsigned)f2bf(v7) << 16);
            *(uint4*)&As[row * KF + ch * 8] = o;
        }
    }
    __syncthreads();

    // ---- K-loop: stage B tiles only ----
    f32x4 acc[MR][NR];
#pragma unroll
    for (int m = 0; m < MR; ++m)
#pragma unroll
        for (int n = 0; n < NR; ++n) acc[m][n] = (f32x4){0.f, 0.f, 0.f, 0.f};

    for (int k0 = 0; k0 < KF; k0 += BK) {
#pragma unroll
        for (int c = 0; c < BIT; ++c) {
            int base = c * 256 + wid * 64;
            int ci = base + lane;
            int row = ci / BCPR, ch = ci % BCPR;
            gload16(BT + (size_t)(colBase + row) * KF + k0 + ((ch ^ (row & 7)) << 3),
                    &Bs[base * 8]);
        }
        __syncthreads();
#pragma unroll
        for (int kk = 0; kk < KK; ++kk) {
            bf16x8 af[MR], bfr[NR];
#pragma unroll
            for (int m = 0; m < MR; ++m) {
                int lr = wm * 32 + m * 16 + r15;
                int off = lr * (KF * 2) + ((k0 * 2 + kk * 64 + g * 16) ^ ((lr & 7) << 4));
                af[m] = *(const bf16x8*)((const char*)As + off);
            }
#pragma unroll
            for (int n = 0; n < NR; ++n) {
                int br = wn * (BN / 2) + n * 16 + r15;
                int off = br * (BK * 2) + ((kk * 64 + g * 16) ^ ((br & 7) << 4));
                bfr[n] = *(const bf16x8*)((const char*)Bs + off);
            }
#pragma unroll
            for (int m = 0; m < MR; ++m)
#pragma unroll
                for (int n = 0; n < NR; ++n)
                    acc[m][n] = __builtin_amdgcn_mfma_f32_16x16x32_bf16(
                        af[m], bfr[n], acc[m][n], 0, 0, 0);
        }
        __syncthreads();
    }
#pragma unroll
    for (int m = 0; m < MR; ++m) {
        int row = rowBase + wm * 32 + m * 16 + g * 4;
#pragma unroll
        for (int n = 0; n < NR; ++n) {
            int col = colBase + wn * (BN / 2) + n * 16 + r15;
            float bv = bias[col];
#pragma unroll
            for (int r = 0; r < 4; ++r)
                C[(size_t)(row + r) * N + col] = f2bf(acc[m][n][r] + bv);
        }
    }
}

extern "C" void kernel_launch(void* const* d_in, const int* in_sizes, int n_in,
                              void* d_out, int out_size, void* d_ws, size_t ws_size,
                              hipStream_t stream) {
    const float* state      = (const float*)d_in[0];
    const float* context    = (const float*)d_in[1];
    const float* edge_attr  = (const float*)d_in[2];
    const int*   edge_index = (const int*)d_in[3];
    const float* ew_w1 = (const float*)d_in[4];
    const float* ew_b1 = (const float*)d_in[5];
    const float* ew_w2 = (const float*)d_in[6];
    const float* ew_b2 = (const float*)d_in[7];
    const float* td_w1 = (const float*)d_in[8];
    const float* td_b1 = (const float*)d_in[9];
    const float* ln1_g = (const float*)d_in[10];
    const float* ln1_b = (const float*)d_in[11];
    const float* td_w2 = (const float*)d_in[12];
    const float* td_b2 = (const float*)d_in[13];
    const float* ln2_g = (const float*)d_in[14];
    const float* ln2_b = (const float*)d_in[15];
    const float* td_w3 = (const float*)d_in[16];
    const float* td_b3 = (const float*)d_in[17];
    const float* df_w1 = (const float*)d_in[18];
    const float* df_b1 = (const float*)d_in[19];
    const float* df_w2 = (const float*)d_in[20];
    const float* df_b2 = (const float*)d_in[21];
    float* out = (float*)d_out;

    float* ws = (float*)d_ws;
    size_t off = 0;
    auto alloc = [&](size_t nfloats) { float* p = ws + off; off += nfloats; return p; };
    float*  ew    = alloc(NEDGE);
    float*  deg   = alloc(N_NODES);
    float*  dis   = alloc(N_NODES);
    float*  ctxp  = alloc((size_t)BATCH * HDIM);
    float*  dc    = alloc(BN_);
    float*  L     = alloc((size_t)N_NODES * N_NODES);                 // 16 MB
    ushort* Lbf   = (ushort*)alloc((size_t)N_NODES * N_NODES / 2);    // 8 MB
    float*  y     = alloc((size_t)BN_ * FDIM);                        // 8 MB
    ushort* yi    = (ushort*)alloc((size_t)BN_ * FDIM / 2);           // 4 MB
    ushort* yiT   = (ushort*)alloc((size_t)BN_ * FDIM / 2);           // 4 MB
    ushort* hcat  = (ushort*)alloc((size_t)BN_ * 768 / 2);            // 12 MB
    ushort* h2b   = (ushort*)alloc((size_t)BN_ * HDIM / 2);           // 8 MB
    ushort* wcat  = (ushort*)alloc((size_t)768 * FDIM / 2);
    ushort* w2T   = (ushort*)alloc((size_t)HDIM * HDIM / 2);
    ushort* w3T   = (ushort*)alloc((size_t)FDIM * HDIM / 2);
    ushort* kb[6];
    for (int s = 0; s < 6; ++s) kb[s] = (ushort*)alloc((size_t)BN_ * FDIM / 2);

    // ---- prep (once per call) ----
    hipMemsetAsync(deg, 0, N_NODES * sizeof(float), stream);
    hipMemsetAsync(L, 0, (size_t)N_NODES * N_NODES * sizeof(float), stream);
    edge_ew_deg<<<NEDGE / 256, 256, 0, stream>>>(edge_attr, edge_index, ew_w1, ew_b1, ew_w2, ew_b2, ew, deg);
    dis_diag<<<N_NODES / 256, 256, 0, stream>>>(deg, dis, L);
    scatter_L<<<NEDGE / 256, 256, 0, stream>>>(edge_index, ew, dis, L);
    cvt_bf16<<<(N_NODES * N_NODES / 4) / 256, 256, 0, stream>>>(L, Lbf);
    ctxproj_kernel<<<BATCH, HDIM, 0, stream>>>(context, td_w1, td_b1, ctxp);
    transpose_cvt<<<dim3(FDIM / 64, HDIM / 64), 256, 0, stream>>>(td_w1, HDIM, wcat, FDIM, HDIM);
    transpose_cvt<<<dim3(FDIM / 64, FDIM / 64), 256, 0, stream>>>(df_w1, FDIM, wcat + (size_t)HDIM * FDIM, FDIM, FDIM);
    transpose_cvt<<<dim3(HDIM / 64, HDIM / 64), 256, 0, stream>>>(td_w2, HDIM, w2T, HDIM, HDIM);
    transpose_cvt<<<dim3(HDIM / 64, FDIM / 64), 256, 0, stream>>>(td_w3, FDIM, w3T, HDIM, FDIM);

    static const double DPA[6][5] = {
        {0, 0, 0, 0, 0},
        {1.0/5, 0, 0, 0, 0},
        {3.0/40, 9.0/40, 0, 0, 0},
        {44.0/45, -56.0/15, 32.0/9, 0, 0},
        {19372.0/6561, -25360.0/2187, 64448.0/6561, -212.0/729, 0},
        {9017.0/3168, -355.0/33, 46732.0/5247, 49.0/176, -5103.0/18656},
    };

    const dim3 cgrid(N_NODES / 64, FDIM / 64, BATCH);
    const float* ycur = state;
    for (int step = 0; step < 4; ++step) {
        for (int s = 0; s < 6; ++s) {
            if (s == 0) {
                if (step == 0)
                    combine_all<<<cgrid, 256, 0, stream>>>(ycur, nullptr, nullptr, nullptr,
                        nullptr, nullptr, 0, 0, 0, 0, 0, nullptr, yi, yiT);
            } else {
                const ushort* p[5] = {nullptr, nullptr, nullptr, nullptr, nullptr};
                float c[5] = {0, 0, 0, 0, 0};
                for (int j = 0; j < s; ++j) { p[j] = kb[j]; c[j] = (float)(DT * DPA[s][j]); }
                combine_all<<<cgrid, 256, 0, stream>>>(ycur, p[0], p[1], p[2], p[3], p[4],
                    c[0], c[1], c[2], c[3], c[4], nullptr, yi, yiT);
            }
            ushort* ks = kb[s];
            // merged G1(+ctx bias) & G4(+df_b1): yi @ wcat^T -> hcat bf16 [8192,768]
            gemm<128, 128, 64, 2, 2, 3, 1><<<dim3(768 / 128, BN_ / 128, 1), 256, 0, stream>>>(
                yi, wcat, ctxp, df_b1, hcat, 768, FDIM, 0, 0, 0);
            // G2 with fused LN1 + dcoef: LN(hcat[:,0:512]) @ w2T^T + td_b2 -> h2b
            gemm_ln<512, 768, 64, 128, 1><<<dim3(HDIM / 64, BN_ / 64), 256, 0, stream>>>(
                hcat, w2T, ln1_g, ln1_b, td_b2, df_w2, df_b2, dc, h2b, HDIM);
            // G3 with fused LN2: LN(h2b) @ w3T^T + td_b3 -> ks
            gemm_ln<512, 512, 64, 128, 0><<<dim3(FDIM / 64, BN_ / 64), 256, 0, stream>>>(
                h2b, w3T, ln2_g, ln2_b, td_b3, nullptr, nullptr, nullptr, ks, FDIM);
            // merged diffusion over batches: [2048,2048] @ yiT^T -> RMW ks -= dc*Lh
            gemm<64, 64, 128, 2, 2, 0, 2><<<dim3(1024 / 64, N_NODES / 64, 1), 256, 0, stream>>>(
                Lbf, yiT, nullptr, dc, ks, 1024, N_NODES, 0, 0, 0);
        }
        float* dstf = (step == 3) ? out : y;
        combine_all<<<cgrid, 256, 0, stream>>>(ycur,
            kb[0], kb[2], kb[3], kb[4], kb[5],
            (float)(DT * 35.0 / 384), (float)(DT * 500.0 / 1113), (float)(DT * 125.0 / 192),
            (float)(DT * -2187.0 / 6784), (float)(DT * 11.0 / 84),
            dstf, (step == 3) ? nullptr : yi, (step == 3) ? nullptr : yiT);
        ycur = y;
    }
    (void)in_sizes; (void)n_in; (void)out_size; (void)ws_size;
}